// Round 1
// baseline (168.875 us; speedup 1.0000x reference)
//
#include <hip/hip_runtime.h>

typedef _Float16 f16;
typedef f16 f16x4 __attribute__((ext_vector_type(4)));
typedef f16 f16x8 __attribute__((ext_vector_type(8)));
typedef float f32x4 __attribute__((ext_vector_type(4)));

// Problem constants
// state_embed (256,512) f32 | action_feats (256,1000,64) f32 | W1 (576,256) | b1 (256)
// W2 (256,128) | b2 (128) | W3 (128,1) | b3 (1)  -> out (256,1000) f32

#define AF_STRIDE 72    // 64 + 8 pad (halves); 144B row = 36 dwords; 36%32=4 -> 16B aligned, good banks
#define H1_STRIDE 264   // 256 + 8 pad; 528B = 132 dwords; 132%32=4
#define H2_STRIDE 136   // 128 + 8 pad; 272B = 68 dwords; 68%32=4

// ---------------- pack W1_a / W2 into MFMA B-fragment lane order (f16) ----------------
// B-frag for mfma_f32_16x16x32_f16: lane L supplies B[k = (L>>4)*8 + j][n = L&15], j=0..7
__global__ __launch_bounds__(256) void pack_weights(const float* __restrict__ W1,
                                                    const float* __restrict__ W2,
                                                    f16* __restrict__ pw1a,
                                                    f16* __restrict__ pw2) {
    int idx = blockIdx.x * 256 + threadIdx.x;   // 0..6143
    int F = idx >> 6;                            // fragment id 0..95
    int L = idx & 63;
    int q = L >> 4, c = L & 15;
    f16x8 v;
    if (F < 32) {                                // W1_a: K=64 (kt 0..1), N=256 (nt 0..15)
        int nt = F >> 1, kt = F & 1;
        #pragma unroll
        for (int j = 0; j < 8; ++j) {
            int k = kt * 32 + q * 8 + j;         // 0..63
            v[j] = (f16)W1[(size_t)(512 + k) * 256 + nt * 16 + c];
        }
        *(f16x8*)(pw1a + ((size_t)F * 64 + L) * 8) = v;
    } else {                                     // W2: K=256 (kt 0..7), N=128 (nt 0..7)
        int F2 = F - 32;
        int nt = F2 >> 3, kt = F2 & 7;
        #pragma unroll
        for (int j = 0; j < 8; ++j) {
            int k = kt * 32 + q * 8 + j;         // 0..255
            v[j] = (f16)W2[(size_t)k * 128 + nt * 16 + c];
        }
        *(f16x8*)(pw2 + ((size_t)F2 * 64 + L) * 8) = v;
    }
}

// ---------------- h_state = state_embed @ W1[:512] + b1   (fp32, exact) ----------------
__global__ __launch_bounds__(256) void hstate_kernel(const float* __restrict__ state,
                                                     const float* __restrict__ W1,
                                                     const float* __restrict__ b1,
                                                     float* __restrict__ hstate) {
    __shared__ float srow[4][512];
    int b0 = blockIdx.x * 4;
    int tid = threadIdx.x;
    #pragma unroll
    for (int i = 0; i < 8; ++i) {
        int e = i * 256 + tid;                  // 0..2047
        srow[e >> 9][e & 511] = state[(size_t)b0 * 512 + e];
    }
    __syncthreads();
    float bias = b1[tid];
    float a0 = bias, a1 = bias, a2 = bias, a3 = bias;
    for (int f = 0; f < 512; ++f) {
        float w = W1[(size_t)f * 256 + tid];    // coalesced 1KB row; srow reads are broadcast
        a0 = fmaf(srow[0][f], w, a0);
        a1 = fmaf(srow[1][f], w, a1);
        a2 = fmaf(srow[2][f], w, a2);
        a3 = fmaf(srow[3][f], w, a3);
    }
    hstate[(size_t)(b0 + 0) * 256 + tid] = a0;
    hstate[(size_t)(b0 + 1) * 256 + tid] = a1;
    hstate[(size_t)(b0 + 2) * 256 + tid] = a2;
    hstate[(size_t)(b0 + 3) * 256 + tid] = a3;
}

// ---------------- fused per-row MLP: 64 rows/block, f16 MFMA ----------------
__global__ __launch_bounds__(256) void fused_kernel(const float* __restrict__ afeat,
                                                    const float* __restrict__ hstate,
                                                    const f16* __restrict__ pw1a,
                                                    const f16* __restrict__ pw2,
                                                    const float* __restrict__ b2,
                                                    const float* __restrict__ W3,
                                                    const float* __restrict__ b3,
                                                    float* __restrict__ out) {
    __shared__ f16 afs[64 * AF_STRIDE];
    __shared__ f16 h1s[64 * H1_STRIDE];
    __shared__ f16 h2s[64 * H2_STRIDE];

    int tid = threadIdx.x;
    int w = tid >> 6;            // wave 0..3
    int L = tid & 63;
    int q = L >> 4, c = L & 15;
    int r0 = blockIdx.x * 64;    // first global row of this tile

    // ---- stage action_feats tile (64 rows x 64 feats), fp32 -> f16 LDS ----
    #pragma unroll
    for (int i = 0; i < 4; ++i) {
        int e = i * 256 + tid;                   // float4-chunk id 0..1023
        int row = e >> 4, c4 = e & 15;
        f32x4 v = *(const f32x4*)(afeat + (size_t)(r0 + row) * 64 + c4 * 4);
        f16x4 hv;
        hv[0] = (f16)v[0]; hv[1] = (f16)v[1]; hv[2] = (f16)v[2]; hv[3] = (f16)v[3];
        *(f16x4*)(afs + row * AF_STRIDE + c4 * 4) = hv;
    }
    __syncthreads();

    // ---- GEMM1: (64x64) @ W1_a(64x256); wave w owns cols [w*64, w*64+63] ----
    // A-frag: lane supplies A[m = L&15][k = q*8+j]
    f16x8 a1[4][2];
    #pragma unroll
    for (int rb = 0; rb < 4; ++rb)
        #pragma unroll
        for (int kt = 0; kt < 2; ++kt)
            a1[rb][kt] = *(const f16x8*)(afs + (rb * 16 + c) * AF_STRIDE + kt * 32 + q * 8);

    f32x4 acc1[4][4];
    #pragma unroll
    for (int rb = 0; rb < 4; ++rb)
        #pragma unroll
        for (int ntl = 0; ntl < 4; ++ntl)
            acc1[rb][ntl] = (f32x4){0.f, 0.f, 0.f, 0.f};

    #pragma unroll
    for (int ntl = 0; ntl < 4; ++ntl) {
        int nt = w * 4 + ntl;
        #pragma unroll
        for (int kt = 0; kt < 2; ++kt) {
            f16x8 bfr = *(const f16x8*)(pw1a + ((size_t)(nt * 2 + kt) * 64 + L) * 8);
            #pragma unroll
            for (int rb = 0; rb < 4; ++rb)
                acc1[rb][ntl] = __builtin_amdgcn_mfma_f32_16x16x32_f16(
                    a1[rb][kt], bfr, acc1[rb][ntl], 0, 0, 0);
        }
    }

    // ---- epilogue 1: + h_state[b(row)] , relu, -> LDS f16 ----
    // C/D: col = L&15, row(in tile) = q*4 + reg. Block spans at most 2 distinct b.
    int b0i = r0 / 1000;
    int boundary = (b0i + 1) * 1000;
    int b1i = b0i < 255 ? b0i + 1 : 255;
    #pragma unroll
    for (int ntl = 0; ntl < 4; ++ntl) {
        int col = (w * 4 + ntl) * 16 + c;
        float hsA = hstate[(size_t)b0i * 256 + col];
        float hsB = hstate[(size_t)b1i * 256 + col];
        #pragma unroll
        for (int rb = 0; rb < 4; ++rb) {
            #pragma unroll
            for (int reg = 0; reg < 4; ++reg) {
                int lrow = rb * 16 + q * 4 + reg;
                float hs = (r0 + lrow >= boundary) ? hsB : hsA;
                float v = acc1[rb][ntl][reg] + hs;
                v = v > 0.f ? v : 0.f;
                h1s[lrow * H1_STRIDE + col] = (f16)v;
            }
        }
    }
    __syncthreads();

    // ---- GEMM2: (64x256) @ W2(256x128); wave w owns cols [w*32, w*32+31] ----
    f32x4 acc2[4][2];
    #pragma unroll
    for (int rb = 0; rb < 4; ++rb) {
        acc2[rb][0] = (f32x4){0.f, 0.f, 0.f, 0.f};
        acc2[rb][1] = (f32x4){0.f, 0.f, 0.f, 0.f};
    }
    #pragma unroll
    for (int kt = 0; kt < 8; ++kt) {
        f16x8 a2[4];
        #pragma unroll
        for (int rb = 0; rb < 4; ++rb)
            a2[rb] = *(const f16x8*)(h1s + (rb * 16 + c) * H1_STRIDE + kt * 32 + q * 8);
        #pragma unroll
        for (int ntl = 0; ntl < 2; ++ntl) {
            int nt = w * 2 + ntl;
            f16x8 bfr = *(const f16x8*)(pw2 + ((size_t)(nt * 8 + kt) * 64 + L) * 8);
            #pragma unroll
            for (int rb = 0; rb < 4; ++rb)
                acc2[rb][ntl] = __builtin_amdgcn_mfma_f32_16x16x32_f16(
                    a2[rb], bfr, acc2[rb][ntl], 0, 0, 0);
        }
    }

    // ---- epilogue 2: + b2, relu, -> LDS f16 ----
    #pragma unroll
    for (int ntl = 0; ntl < 2; ++ntl) {
        int col = (w * 2 + ntl) * 16 + c;
        float bias = b2[col];
        #pragma unroll
        for (int rb = 0; rb < 4; ++rb) {
            #pragma unroll
            for (int reg = 0; reg < 4; ++reg) {
                int lrow = rb * 16 + q * 4 + reg;
                float v = acc2[rb][ntl][reg] + bias;
                v = v > 0.f ? v : 0.f;
                h2s[lrow * H2_STRIDE + col] = (f16)v;
            }
        }
    }
    __syncthreads();

    // ---- layer 3: logits = h2 @ W3 + b3 (fp32 vector), 4 threads per row ----
    int row = tid >> 2, part = tid & 3;
    float acc = 0.f;
    #pragma unroll
    for (int i = 0; i < 4; ++i) {
        f16x8 hv = *(const f16x8*)(h2s + row * H2_STRIDE + part * 32 + i * 8);
        #pragma unroll
        for (int j = 0; j < 8; ++j)
            acc = fmaf((float)hv[j], W3[part * 32 + i * 8 + j], acc);
    }
    acc += __shfl_xor(acc, 1);
    acc += __shfl_xor(acc, 2);
    if ((tid & 3) == 0) out[r0 + row] = acc + b3[0];
}

extern "C" void kernel_launch(void* const* d_in, const int* in_sizes, int n_in,
                              void* d_out, int out_size, void* d_ws, size_t ws_size,
                              hipStream_t stream) {
    const float* state = (const float*)d_in[0];
    const float* afeat = (const float*)d_in[1];
    const float* W1    = (const float*)d_in[2];
    const float* b1    = (const float*)d_in[3];
    const float* W2    = (const float*)d_in[4];
    const float* b2    = (const float*)d_in[5];
    const float* W3    = (const float*)d_in[6];
    const float* b3    = (const float*)d_in[7];
    float* out = (float*)d_out;

    // workspace: hstate (256*256 f32 = 256KB) | pw1a (16384 f16 = 32KB) | pw2 (32768 f16 = 64KB)
    float* hstate = (float*)d_ws;
    f16* pw1a = (f16*)((char*)d_ws + 65536 * sizeof(float));
    f16* pw2  = pw1a + 16384;

    pack_weights<<<24, 256, 0, stream>>>(W1, W2, pw1a, pw2);
    hstate_kernel<<<64, 256, 0, stream>>>(state, W1, b1, hstate);
    fused_kernel<<<4000, 256, 0, stream>>>(afeat, hstate, pw1a, pw2, b2, W3, b3, out);
}

// Round 2
// 156.032 us; speedup vs baseline: 1.0823x; 1.0823x over previous
//
#include <hip/hip_runtime.h>

typedef _Float16 f16;
typedef f16 f16x4 __attribute__((ext_vector_type(4)));
typedef f16 f16x8 __attribute__((ext_vector_type(8)));
typedef float f32x4 __attribute__((ext_vector_type(4)));

// state_embed (256,512) f32 | action_feats (256,1000,64) f32 | W1 (576,256) | b1 (256)
// W2 (256,128) | b2 (128) | W3 (128,1) | b3 (1)  -> out (256,1000) f32

#define AF_STRIDE 72    // 64+8 f16; 36 dwords/row, 36%32=4 -> b128/b64 2-way (free)
#define H1_STRIDE 264   // 256+8 f16; 132 dwords/row, 132%32=4 -> 2-way (free)

// ---------- prep: pack W1a^T (A-frag order), W2 (B-frag order), compute h_state ----------
// A-frag (16x16x32): lane L holds A[m=L&15][k=(L>>4)*8+j], j=0..7
// B-frag:            lane L holds B[k=(L>>4)*8+j][n=L&15]
__global__ __launch_bounds__(256) void prep_kernel(const float* __restrict__ W1,
                                                   const float* __restrict__ W2,
                                                   const float* __restrict__ state,
                                                   const float* __restrict__ b1,
                                                   f16* __restrict__ pw1at,
                                                   f16* __restrict__ pw2,
                                                   float* __restrict__ hstate) {
    __shared__ float srow[4][512];
    int blk = blockIdx.x;
    int tid = threadIdx.x;
    if (blk < 24) {
        int idx = blk * 256 + tid;              // 0..6143
        int F = idx >> 6;                       // fragment id 0..95
        int L = idx & 63;
        int q = L >> 4, c = L & 15;
        f16x8 v;
        if (F < 32) {                           // pw1at = W1_a^T as A-frags: M=256h (mt 0..15), K=64f (kt 0..1)
            int mt = F >> 1, kt = F & 1;
            #pragma unroll
            for (int j = 0; j < 8; ++j) {
                int f = kt * 32 + q * 8 + j;    // feat 0..63
                v[j] = (f16)W1[(size_t)(512 + f) * 256 + mt * 16 + c];  // W1a^T[h][f] = W1[512+f][h]
            }
            *(f16x8*)(pw1at + ((size_t)F * 64 + L) * 8) = v;
        } else {                                // pw2 = W2 as B-frags: K=256 (kt 0..7), N=128 (nt 0..7)
            int F2 = F - 32;
            int nt = F2 >> 3, kt = F2 & 7;
            #pragma unroll
            for (int j = 0; j < 8; ++j) {
                int k = kt * 32 + q * 8 + j;
                v[j] = (f16)W2[(size_t)k * 128 + nt * 16 + c];
            }
            *(f16x8*)(pw2 + ((size_t)F2 * 64 + L) * 8) = v;
        }
    } else {
        // h_state = state_embed @ W1[:512] + b1 (fp32 exact), 4 batch rows per block
        int b0 = (blk - 24) * 4;
        #pragma unroll
        for (int i = 0; i < 8; ++i) {
            int e = i * 256 + tid;
            srow[e >> 9][e & 511] = state[(size_t)b0 * 512 + e];
        }
        __syncthreads();
        float bias = b1[tid];
        float a0 = bias, a1 = bias, a2 = bias, a3 = bias;
        for (int f = 0; f < 512; ++f) {
            float wv = W1[(size_t)f * 256 + tid];
            a0 = fmaf(srow[0][f], wv, a0);
            a1 = fmaf(srow[1][f], wv, a1);
            a2 = fmaf(srow[2][f], wv, a2);
            a3 = fmaf(srow[3][f], wv, a3);
        }
        hstate[(size_t)(b0 + 0) * 256 + tid] = a0;
        hstate[(size_t)(b0 + 1) * 256 + tid] = a1;
        hstate[(size_t)(b0 + 2) * 256 + tid] = a2;
        hstate[(size_t)(b0 + 3) * 256 + tid] = a3;
    }
}

// ---------- fused per-row MLP: 64 action-rows per block ----------
__global__ __launch_bounds__(256) void fused_kernel(const float* __restrict__ afeat,
                                                    const float* __restrict__ hstate,
                                                    const f16* __restrict__ pw1at,
                                                    const f16* __restrict__ pw2,
                                                    const float* __restrict__ b2,
                                                    const float* __restrict__ W3,
                                                    const float* __restrict__ b3,
                                                    float* __restrict__ out) {
    __shared__ f16 afs[64 * AF_STRIDE];     //  9216 B
    __shared__ f16 h1s[64 * H1_STRIDE];     // 33792 B
    __shared__ float lds3[256];             //  1024 B   -> total 43 KB -> 3 blocks/CU

    int tid = threadIdx.x;
    int w = tid >> 6;                // wave 0..3
    int L = tid & 63;
    int q = L >> 4, c = L & 15;
    int r0 = blockIdx.x * 64;

    // ---- preload this wave's A-frags (W1a^T), in flight across staging+barrier ----
    f16x8 a1f[4][2];                 // mt = 4w+i (h 64w..64w+63), kt 0..1
    #pragma unroll
    for (int i = 0; i < 4; ++i)
        #pragma unroll
        for (int kt = 0; kt < 2; ++kt)
            a1f[i][kt] = *(const f16x8*)(pw1at + ((size_t)((4 * w + i) * 2 + kt) * 64 + L) * 8);

    // ---- stage action_feats tile (64x64) fp32 -> f16 LDS ----
    #pragma unroll
    for (int i = 0; i < 4; ++i) {
        int e = i * 256 + tid;
        int row = e >> 4, c4 = e & 15;
        f32x4 v = *(const f32x4*)(afeat + (size_t)(r0 + row) * 64 + c4 * 4);
        f16x4 hv;
        hv[0] = (f16)v[0]; hv[1] = (f16)v[1]; hv[2] = (f16)v[2]; hv[3] = (f16)v[3];
        *(f16x4*)(afs + row * AF_STRIDE + c4 * 4) = hv;
    }
    __syncthreads();

    // ---- GEMM1 (swapped): h1^T(256x64) = W1a^T(256x64f) @ afeat^T(64f x 64rows) ----
    // B-frag of afeat^T: lane needs afeat[row=nt*16+c][f=kt*32+q*8+j] -> contiguous b128
    f16x8 bf[4][2];
    #pragma unroll
    for (int nt = 0; nt < 4; ++nt)
        #pragma unroll
        for (int kt = 0; kt < 2; ++kt)
            bf[nt][kt] = *(const f16x8*)(afs + (nt * 16 + c) * AF_STRIDE + kt * 32 + q * 8);

    f32x4 acc1[4][4];
    #pragma unroll
    for (int i = 0; i < 4; ++i)
        #pragma unroll
        for (int nt = 0; nt < 4; ++nt)
            acc1[i][nt] = (f32x4){0.f, 0.f, 0.f, 0.f};

    #pragma unroll
    for (int i = 0; i < 4; ++i)
        #pragma unroll
        for (int nt = 0; nt < 4; ++nt)
            #pragma unroll
            for (int kt = 0; kt < 2; ++kt)
                acc1[i][nt] = __builtin_amdgcn_mfma_f32_16x16x32_f16(
                    a1f[i][kt], bf[nt][kt], acc1[i][nt], 0, 0, 0);

    // ---- epilogue 1: D[m=h][n=row]; lane: rows q*4+reg are 4 consecutive h, col c = action row ----
    int b0i = r0 / 1000;
    int boundary = (b0i + 1) * 1000;
    int b1i = b0i < 255 ? b0i + 1 : 255;
    #pragma unroll
    for (int i = 0; i < 4; ++i) {
        int hbase = (4 * w + i) * 16 + q * 4;               // 4 consecutive h start
        f32x4 hsA = *(const f32x4*)(hstate + (size_t)b0i * 256 + hbase);
        f32x4 hsB = *(const f32x4*)(hstate + (size_t)b1i * 256 + hbase);
        #pragma unroll
        for (int nt = 0; nt < 4; ++nt) {
            int rowg = r0 + nt * 16 + c;
            bool sel = rowg >= boundary;
            f16x4 hv;
            #pragma unroll
            for (int reg = 0; reg < 4; ++reg) {
                float v = acc1[i][nt][reg] + (sel ? hsB[reg] : hsA[reg]);
                v = v > 0.f ? v : 0.f;
                hv[reg] = (f16)v;
            }
            *(f16x4*)(h1s + (nt * 16 + c) * H1_STRIDE + hbase) = hv;  // vector b64 store
        }
    }
    __syncthreads();

    // ---- GEMM2: h2(64x128) = h1(64x256) @ W2; wave w owns cols [w*32, w*32+31] ----
    f32x4 acc2[4][2];
    #pragma unroll
    for (int rb = 0; rb < 4; ++rb) {
        acc2[rb][0] = (f32x4){0.f, 0.f, 0.f, 0.f};
        acc2[rb][1] = (f32x4){0.f, 0.f, 0.f, 0.f};
    }
    #pragma unroll
    for (int kt = 0; kt < 8; ++kt) {
        f16x8 a2[4];
        #pragma unroll
        for (int rb = 0; rb < 4; ++rb)
            a2[rb] = *(const f16x8*)(h1s + (rb * 16 + c) * H1_STRIDE + kt * 32 + q * 8);
        #pragma unroll
        for (int ntl = 0; ntl < 2; ++ntl) {
            f16x8 bfr = *(const f16x8*)(pw2 + ((size_t)((w * 2 + ntl) * 8 + kt) * 64 + L) * 8);
            #pragma unroll
            for (int rb = 0; rb < 4; ++rb)
                acc2[rb][ntl] = __builtin_amdgcn_mfma_f32_16x16x32_f16(
                    a2[rb], bfr, acc2[rb][ntl], 0, 0, 0);
        }
    }

    // ---- layer 3 in-register: logit[row] = sum_col relu(acc2+b2[col]) * W3[col] + b3 ----
    float b2v[2], w3v[2];
    #pragma unroll
    for (int ntl = 0; ntl < 2; ++ntl) {
        int col = (w * 2 + ntl) * 16 + c;
        b2v[ntl] = b2[col];
        w3v[ntl] = W3[col];
    }
    #pragma unroll
    for (int rb = 0; rb < 4; ++rb) {
        #pragma unroll
        for (int reg = 0; reg < 4; ++reg) {
            float p = 0.f;
            #pragma unroll
            for (int ntl = 0; ntl < 2; ++ntl) {
                float v = acc2[rb][ntl][reg] + b2v[ntl];
                v = v > 0.f ? v : 0.f;
                p = fmaf(v, w3v[ntl], p);
            }
            // reduce over c (lane bits 0..3)
            p += __shfl_xor(p, 1);
            p += __shfl_xor(p, 2);
            p += __shfl_xor(p, 4);
            p += __shfl_xor(p, 8);
            if (c == 0) lds3[(rb * 16 + q * 4 + reg) * 4 + w] = p;
        }
    }
    __syncthreads();
    if (tid < 64) {
        f32x4 s = *(const f32x4*)(lds3 + tid * 4);
        out[r0 + tid] = s[0] + s[1] + s[2] + s[3] + b3[0];
    }
}

extern "C" void kernel_launch(void* const* d_in, const int* in_sizes, int n_in,
                              void* d_out, int out_size, void* d_ws, size_t ws_size,
                              hipStream_t stream) {
    const float* state = (const float*)d_in[0];
    const float* afeat = (const float*)d_in[1];
    const float* W1    = (const float*)d_in[2];
    const float* b1    = (const float*)d_in[3];
    const float* W2    = (const float*)d_in[4];
    const float* b2    = (const float*)d_in[5];
    const float* W3    = (const float*)d_in[6];
    const float* b3    = (const float*)d_in[7];
    float* out = (float*)d_out;

    // ws: hstate 256KB | pw1at 32KB (16384 f16) | pw2 64KB (32768 f16)
    float* hstate = (float*)d_ws;
    f16* pw1at = (f16*)((char*)d_ws + 65536 * sizeof(float));
    f16* pw2   = pw1at + 16384;

    prep_kernel<<<88, 256, 0, stream>>>(W1, W2, state, b1, pw1at, pw2, hstate);
    fused_kernel<<<4000, 256, 0, stream>>>(afeat, hstate, pw1at, pw2, b2, W3, b3, out);
}